// Round 1
// baseline (444.323 us; speedup 1.0000x reference)
//
#include <hip/hip_runtime.h>

#define NN   4096
#define MAXD 32
#define TB   4

// Phase 1: build ELL (column-major [j][o]) of W*M, deterministically.
// One wave (64 lanes) per output row o; ballot + prefix popcount keeps
// neighbor indices sorted ascending -> fixed fp32 summation order.
__global__ __launch_bounds__(64) void build_ell_kernel(
    const float* __restrict__ weight, const float* __restrict__ mask,
    unsigned short* __restrict__ ell_idx, float* __restrict__ ell_w,
    int* __restrict__ cnt) {
  const int o = blockIdx.x;
  const int lane = threadIdx.x;
  const float* mrow = mask + (size_t)o * NN;
  const float* wrow = weight + (size_t)o * NN;
  int count = 0;
  for (int base = 0; base < NN; base += 64) {
    const float m = mrow[base + lane];
    const bool nz = (m != 0.0f);
    const unsigned long long bal = __ballot(nz);
    if (nz) {
      const int pos = count + __popcll(bal & ((1ull << lane) - 1ull));
      if (pos < MAXD) {
        ell_idx[(size_t)pos * NN + o] = (unsigned short)(base + lane);
        ell_w[(size_t)pos * NN + o]   = wrow[base + lane] * m;  // m==1.0 exactly
      }
    }
    count += __popcll(bal);
  }
  if (lane == 0) cnt[o] = (count < MAXD) ? count : MAXD;
}

// Phase 2: SpMM. Block stages TB token rows into LDS (coalesced float4),
// then each thread computes outputs o = ob+tid for all TB tokens via
// LDS gathers. Coalesced out writes; bias added once.
__global__ __launch_bounds__(256) void ws_spmm_kernel(
    const float* __restrict__ x, const float* __restrict__ bias,
    const unsigned short* __restrict__ ell_idx, const float* __restrict__ ell_w,
    const int* __restrict__ cnt, float* __restrict__ out) {
  __shared__ float xs[TB * NN];                      // 64 KiB
  const int tid = threadIdx.x;
  const size_t t0 = (size_t)blockIdx.x * TB;

  // Stage TB rows of x: TB*NN/4 = 4096 float4, 16 per thread, coalesced.
  const float4* __restrict__ xg = (const float4*)(x + t0 * NN);
  float4* xsv = (float4*)xs;
#pragma unroll
  for (int i = 0; i < (TB * NN / 4) / 256; ++i)
    xsv[tid + i * 256] = xg[tid + i * 256];
  __syncthreads();

  for (int ob = 0; ob < NN; ob += 256) {
    const int o = ob + tid;
    const int c = cnt[o];
    float acc0 = 0.f, acc1 = 0.f, acc2 = 0.f, acc3 = 0.f;
    for (int j = 0; j < c; ++j) {
      const int   ix = ell_idx[(size_t)j * NN + o];  // coalesced u16
      const float w  = ell_w[(size_t)j * NN + o];    // coalesced f32
      acc0 = fmaf(xs[ix],          w, acc0);
      acc1 = fmaf(xs[NN + ix],     w, acc1);
      acc2 = fmaf(xs[2 * NN + ix], w, acc2);
      acc3 = fmaf(xs[3 * NN + ix], w, acc3);
    }
    const float b = bias[o];
    float* op = out + t0 * NN + o;
    op[0]      = acc0 + b;
    op[NN]     = acc1 + b;
    op[2 * NN] = acc2 + b;
    op[3 * NN] = acc3 + b;
  }
}

extern "C" void kernel_launch(void* const* d_in, const int* in_sizes, int n_in,
                              void* d_out, int out_size, void* d_ws, size_t ws_size,
                              hipStream_t stream) {
  const float* x      = (const float*)d_in[0];
  const float* weight = (const float*)d_in[1];
  const float* bias   = (const float*)d_in[2];
  const float* mask   = (const float*)d_in[3];
  float* out = (float*)d_out;

  char* ws = (char*)d_ws;
  float*          ell_w   = (float*)ws;                                  // 512 KiB
  unsigned short* ell_idx = (unsigned short*)(ws + (size_t)MAXD * NN * sizeof(float)); // 256 KiB
  int*            cnt     = (int*)(ws + (size_t)MAXD * NN * (sizeof(float) + sizeof(unsigned short)));

  const int tokens = in_sizes[0] / NN;               // 16384

  build_ell_kernel<<<NN, 64, 0, stream>>>(weight, mask, ell_idx, ell_w, cnt);
  ws_spmm_kernel<<<tokens / TB, 256, 0, stream>>>(x, bias, ell_idx, ell_w, cnt, out);
}

// Round 2
// 183.555 us; speedup vs baseline: 2.4207x; 2.4207x over previous
//
#include <hip/hip_runtime.h>

#define NN    4096
#define MAXD  32      // storage width (degree cap; WS k=4 max degree ~12)
#define WUNR  8       // fully-unrolled fixed width; rows with c>8 take tail loop
#define TB    4       // tokens staged per block
#define BLK   512

// Phase 1: build padded ELL (column-major [j][o]) of W*M, deterministically.
// One wave per output row o; ballot + prefix popcount keeps indices sorted
// ascending -> fixed fp32 summation order. Entries packed as float2
// { idx (as uint bitcast), w }; entries j in [c, MAXD) are {0, 0.0f}.
__global__ __launch_bounds__(64) void build_ell_kernel(
    const float* __restrict__ weight, const float* __restrict__ mask,
    float2* __restrict__ ell, int* __restrict__ cnt) {
  const int o = blockIdx.x;
  const int lane = threadIdx.x;
  // zero-init padding
  if (lane < MAXD) {
    float2 z; z.x = __uint_as_float(0u); z.y = 0.0f;
    ell[(size_t)lane * NN + o] = z;
  }
  __syncthreads();
  const float* mrow = mask + (size_t)o * NN;
  const float* wrow = weight + (size_t)o * NN;
  int count = 0;
  for (int base = 0; base < NN; base += 64) {
    const float m = mrow[base + lane];
    const bool nz = (m != 0.0f);
    const unsigned long long bal = __ballot(nz);
    if (nz) {
      const int pos = count + __popcll(bal & ((1ull << lane) - 1ull));
      if (pos < MAXD) {
        float2 e;
        e.x = __uint_as_float((unsigned)(base + lane));
        e.y = wrow[base + lane] * m;   // m == 1.0 exactly
        ell[(size_t)pos * NN + o] = e;
      }
    }
    count += __popcll(bal);
  }
  if (lane == 0) cnt[o] = (count < MAXD) ? count : MAXD;
}

// Phase 2: SpMM. Block stages TB token rows into LDS (coalesced float4),
// then each thread computes outputs o = ob+tid for all TB tokens.
// First WUNR ELL entries fully unrolled (8 independent dwordx2 loads +
// 32 independent LDS gathers -> deep ILP); rare c>WUNR rows take a tail loop.
__global__ __launch_bounds__(BLK) void ws_spmm_kernel(
    const float* __restrict__ x, const float* __restrict__ bias,
    const float2* __restrict__ ell, const int* __restrict__ cnt,
    float* __restrict__ out) {
  __shared__ float xs[TB * NN];                      // 64 KiB
  const int tid = threadIdx.x;
  const size_t t0 = (size_t)blockIdx.x * TB;

  // Stage TB rows of x: TB*NN/4 = 4096 float4, BLK threads -> 8 each.
  const float4* __restrict__ xg = (const float4*)(x + t0 * NN);
  float4* xsv = (float4*)xs;
#pragma unroll
  for (int i = 0; i < (TB * NN / 4) / BLK; ++i)
    xsv[tid + i * BLK] = xg[tid + i * BLK];
  __syncthreads();

  for (int ob = 0; ob < NN; ob += BLK) {
    const int o = ob + tid;
    const int c = cnt[o];

    float2 e[WUNR];
#pragma unroll
    for (int j = 0; j < WUNR; ++j)
      e[j] = ell[(size_t)j * NN + o];                // coalesced dwordx2, L2-hit

    float acc0 = 0.f, acc1 = 0.f, acc2 = 0.f, acc3 = 0.f;
#pragma unroll
    for (int j = 0; j < WUNR; ++j) {
      const unsigned ix = __float_as_uint(e[j].x);
      const float w = e[j].y;
      acc0 = fmaf(xs[ix],          w, acc0);
      acc1 = fmaf(xs[NN + ix],     w, acc1);
      acc2 = fmaf(xs[2 * NN + ix], w, acc2);
      acc3 = fmaf(xs[3 * NN + ix], w, acc3);
    }
    // rare tail (degree > WUNR)
    for (int j = WUNR; j < c; ++j) {
      const float2 et = ell[(size_t)j * NN + o];
      const unsigned ix = __float_as_uint(et.x);
      const float w = et.y;
      acc0 = fmaf(xs[ix],          w, acc0);
      acc1 = fmaf(xs[NN + ix],     w, acc1);
      acc2 = fmaf(xs[2 * NN + ix], w, acc2);
      acc3 = fmaf(xs[3 * NN + ix], w, acc3);
    }

    const float b = bias[o];
    float* op = out + t0 * NN + o;
    op[0]      = acc0 + b;
    op[NN]     = acc1 + b;
    op[2 * NN] = acc2 + b;
    op[3 * NN] = acc3 + b;
  }
}

extern "C" void kernel_launch(void* const* d_in, const int* in_sizes, int n_in,
                              void* d_out, int out_size, void* d_ws, size_t ws_size,
                              hipStream_t stream) {
  const float* x      = (const float*)d_in[0];
  const float* weight = (const float*)d_in[1];
  const float* bias   = (const float*)d_in[2];
  const float* mask   = (const float*)d_in[3];
  float* out = (float*)d_out;

  char* ws = (char*)d_ws;
  float2* ell = (float2*)ws;                                   // 32*4096*8 = 1 MiB
  int*    cnt = (int*)(ws + (size_t)MAXD * NN * sizeof(float2)); // 16 KiB

  const int tokens = in_sizes[0] / NN;               // 16384

  build_ell_kernel<<<NN, 64, 0, stream>>>(weight, mask, ell, cnt);
  ws_spmm_kernel<<<tokens / TB, BLK, 0, stream>>>(x, bias, ell, cnt, out);
}